// Round 3
// baseline (331.432 us; speedup 1.0000x reference)
//
#include <hip/hip_runtime.h>
#include <hip/hip_bf16.h>
#include <math.h>

// DCNv2 forward: offset/mod conv -> bilinear deform sample -> main conv (bf16 MFMA)
// x [4,64,192,192] f32; w_off [18,64,3,3]; b_off[18]; w_mod [9,64,3,3]; b_mod[9];
// w [64,64,3,3]; b[64]; out [4,64,192,192] f32.

#define NB   4
#define CIN  64
#define COUT 64
#define HH   192
#define WW   192
#define HW   (HH*WW)

typedef __attribute__((ext_vector_type(4))) float f32x4;
typedef __attribute__((ext_vector_type(8))) short bf16x8;
typedef __attribute__((ext_vector_type(4))) unsigned int u32x4;

__device__ __forceinline__ int iclamp(int v, int lo, int hi) {
    return v < lo ? lo : (v > hi ? hi : v);
}
__device__ __forceinline__ unsigned short bf16bits(float f) {
    __hip_bfloat16 h = __float2bfloat16(f);
    return *reinterpret_cast<unsigned short*>(&h);
}
__device__ __forceinline__ float b2f(unsigned short u) {
    union { unsigned int i; float f; } t;
    t.i = ((unsigned int)u) << 16;
    return t.f;
}

// ---------------------------------------------------------------------------
// Kernel A: x f32 -> bf16 copy (xh). 8 elems/thread.
// ---------------------------------------------------------------------------
__global__ __launch_bounds__(256) void to_bf16(
        const float* __restrict__ x, unsigned short* __restrict__ xh) {
    int t = blockIdx.x * 256 + threadIdx.x;         // 0 .. 1179647
    const f32x4* xv = (const f32x4*)x;
    f32x4 a = xv[2 * t], b = xv[2 * t + 1];
    union { unsigned short us[8]; u32x4 q; } p;
#pragma unroll
    for (int i = 0; i < 4; i++) p.us[i] = bf16bits(a[i]);
#pragma unroll
    for (int i = 0; i < 4; i++) p.us[4 + i] = bf16bits(b[i]);
    ((u32x4*)xh)[t] = p.q;
}

// ---------------------------------------------------------------------------
// Kernel 0: weight repack (wfrag = main weights in MFMA A-frag order, bf16;
// waux[r=c*9+kk][28] = 27 aux out-channels contiguous).
// ---------------------------------------------------------------------------
__global__ __launch_bounds__(256) void prep_weights(
        const float* __restrict__ w, const float* __restrict__ w_off,
        const float* __restrict__ w_mod, __hip_bfloat16* __restrict__ wfrag,
        float* __restrict__ waux) {
    int idx = blockIdx.x * 256 + threadIdx.x;
    if (idx < 36864) {
        int j    = idx & 7;
        int lane = (idx >> 3) & 63;
        int kc   = (idx >> 9) & 1;
        int g    = (idx >> 10) & 3;
        int k    = idx >> 12;
        int o = g * 16 + (lane & 15);
        int c = kc * 32 + (lane >> 4) * 8 + j;
        wfrag[idx] = __float2bfloat16(w[(o * 64 + c) * 9 + k]);
    }
    if (idx < 576 * 28) {
        int r = idx / 28, j = idx % 28;
        float v = 0.f;
        if (j < 18)      v = w_off[j * 576 + r];
        else if (j < 27) v = w_mod[(j - 18) * 576 + r];
        waux[idx] = v;
    }
}

// ---------------------------------------------------------------------------
// Kernel 1a: aux conv partial — half the input channels (h = blockIdx.y).
// part[h][n][j][HW] accumulates 32-channel partial sums (no bias).
// ---------------------------------------------------------------------------
__global__ __launch_bounds__(192) void aux_part(
        const unsigned short* __restrict__ xh, const float* __restrict__ waux,
        float* __restrict__ part) {
    int id = blockIdx.x;                       // 0..767
    int h  = blockIdx.y;                       // 0..1 channel half
    int sw = (id & 7) * 96 + (id >> 3);        // bijective XCD swizzle
    int n  = sw / HH;
    int ho = sw % HH;
    int wo = threadIdx.x;

    float acc[27];
#pragma unroll
    for (int j = 0; j < 27; j++) acc[j] = 0.f;

    const unsigned short* xn = xh + (n * CIN + h * 32) * HW;
    for (int c = 0; c < 32; c++) {
        const unsigned short* xc = xn + c * HW;
        int ci = h * 32 + c;
#pragma unroll
        for (int ky = 0; ky < 3; ky++) {
            int ys = ho + ky - 1;
            if ((unsigned)ys >= (unsigned)HH) continue;
#pragma unroll
            for (int kx = 0; kx < 3; kx++) {
                int xs = wo + kx - 1;
                float xv = ((unsigned)xs < (unsigned)WW) ? b2f(xc[ys * WW + xs]) : 0.f;
                const float* wp = waux + (ci * 9 + ky * 3 + kx) * 28;  // uniform
#pragma unroll
                for (int j = 0; j < 27; j++)
                    acc[j] = fmaf(wp[j], xv, acc[j]);
            }
        }
    }

    float* pp = part + (((h * NB + n) * 27) * HH + ho) * WW + wo;
#pragma unroll
    for (int j = 0; j < 27; j++) pp[j * HW] = acc[j];
}

// ---------------------------------------------------------------------------
// Kernel 1b: combine halves + bias; ch<18 raw offsets, ch>=18 2*sigmoid.
// 4 elems/thread, vectorized.
// ---------------------------------------------------------------------------
__global__ __launch_bounds__(256) void aux_combine(
        const float* __restrict__ part, const float* __restrict__ b_off,
        const float* __restrict__ b_mod, float* __restrict__ offmod) {
    int t = blockIdx.x * 256 + threadIdx.x;     // 0..995327
    int e = t * 4;
    int n   = e / (27 * HW);
    int r   = e % (27 * HW);
    int j   = r / HW;
    int pix = r % HW;
    f32x4 p0 = *(const f32x4*)(part + ((n * 27 + j) * HW + pix));
    f32x4 p1 = *(const f32x4*)(part + (((NB + n) * 27 + j) * HW + pix));
    float bb = (j < 18) ? b_off[j] : b_mod[j - 18];
    f32x4 s = p0 + p1;
    f32x4 o;
#pragma unroll
    for (int i = 0; i < 4; i++) {
        float v = s[i] + bb;
        o[i] = (j < 18) ? v : 2.f / (1.f + expf(-v));
    }
    *(f32x4*)(offmod + (n * 27 + j) * HW + pix) = o;
}

// ---------------------------------------------------------------------------
// Kernel 2: deformable sampling (bf16 x) + bf16-MFMA main conv + bias + relu.
// Block = 4 waves; per tap: wave g samples ch [16g,16g+16) (explicit register
// batch of 64 ushort gathers -> MLP), packs bf16, writes swizzled LDS,
// barrier, 8 MFMA. offmod prefetched one tap ahead; mod folded into bilinear
// weights; rolled k-loop (I-cache).
// ---------------------------------------------------------------------------
__global__ __launch_bounds__(256, 3) void dcn_main(
        const unsigned short* __restrict__ xh,
        const __hip_bfloat16* __restrict__ wfrag,
        const float* __restrict__ bias, const float* __restrict__ offmod,
        float* __restrict__ out) {
    __shared__ __align__(16) char lds[2][64 * 128];

    int tid = threadIdx.x;
    int l   = tid & 63;
    int g   = __builtin_amdgcn_readfirstlane(tid >> 6);

    int id = blockIdx.x;                        // 0..2303
    int sw = (id & 7) * 288 + (id >> 3);        // bijective XCD swizzle
    int n  = sw / 576;
    int r  = sw % 576;
    int ho = r / 3;
    int wx = r % 3;
    int wo = wx * 64 + l;

    const float* om = offmod + (n * 27 * HH + ho) * WW + wo;
    const unsigned short* xb = xh + (n * CIN + g * 16) * HW;

    f32x4 acc[4];
#pragma unroll
    for (int nf = 0; nf < 4; nf++) acc[nf] = (f32x4){0.f, 0.f, 0.f, 0.f};

    int xorw = (l & 7) << 4;

    // prefetch tap-0 offsets
    float offy = om[0];
    float offx = om[HW];
    float mm   = om[18 * HW];

#pragma unroll 1
    for (int k = 0; k < 9; k++) {
        // A fragments for this tap (L1/L2-hot, issued early)
        const bf16x8* wf = ((const bf16x8*)wfrag) + ((k * 4 + g) * 2) * 64 + l;
        bf16x8 a0 = wf[0];
        bf16x8 a1 = wf[64];

        // --- geometry from prefetched offsets ---
        int ky = k / 3, kx = k - 3 * (k / 3);
        float py = offy + (float)(ho - 1 + ky);
        float px = offx + (float)(wo - 1 + kx);
        float y0f = floorf(py), x0f = floorf(px);
        float ly = py - y0f, lx = px - x0f;
        int y0 = (int)y0f, x0 = (int)x0f;
        int y1 = y0 + 1, x1 = x0 + 1;
        bool y0ok = (unsigned)y0 < (unsigned)HH, y1ok = (unsigned)y1 < (unsigned)HH;
        bool x0ok = (unsigned)x0 < (unsigned)WW, x1ok = (unsigned)x1 < (unsigned)WW;
        float w00 = (y0ok && x0ok) ? mm * (1.f - ly) * (1.f - lx) : 0.f;
        float w01 = (y0ok && x1ok) ? mm * (1.f - ly) * lx         : 0.f;
        float w10 = (y1ok && x0ok) ? mm * ly * (1.f - lx)         : 0.f;
        float w11 = (y1ok && x1ok) ? mm * ly * lx                 : 0.f;
        int y0c = iclamp(y0, 0, HH - 1), y1c = iclamp(y1, 0, HH - 1);
        int x0c = iclamp(x0, 0, WW - 1), x1c = iclamp(x1, 0, WW - 1);
        int o00 = y0c * WW + x0c, o01 = y0c * WW + x1c;
        int o10 = y1c * WW + x0c, o11 = y1c * WW + x1c;

        // --- prefetch next tap's offsets (hides L2 latency under gathers) ---
        if (k < 8) {
            offy = om[(2 * k + 2) * HW];
            offx = om[(2 * k + 3) * HW];
            mm   = om[(19 + k) * HW];
        }

        // --- 64 bf16 gathers into registers (max MLP), then pack ---
        unsigned short s[16][4];
#pragma unroll
        for (int i = 0; i < 16; i++) {
            const unsigned short* xc = xb + i * HW;
            s[i][0] = xc[o00];
            s[i][1] = xc[o01];
            s[i][2] = xc[o10];
            s[i][3] = xc[o11];
        }
        union { unsigned short us[16]; u32x4 q[2]; } pk;
#pragma unroll
        for (int i = 0; i < 16; i++) {
            float v = b2f(s[i][0]) * w00;
            v = fmaf(b2f(s[i][1]), w01, v);
            v = fmaf(b2f(s[i][2]), w10, v);
            v = fmaf(b2f(s[i][3]), w11, v);
            pk.us[i] = bf16bits(v);
        }
        char* buf = lds[k & 1];
        int b0 = l * 128 + g * 32;
        *(u32x4*)(buf + ((b0)      ^ xorw)) = pk.q[0];
        *(u32x4*)(buf + ((b0 + 16) ^ xorw)) = pk.q[1];

        __syncthreads();

        // --- 8 MFMA: D[o=16g..][p] += A(16x32) * V(32x64) ---
#pragma unroll
        for (int nf = 0; nf < 4; nf++) {
            int p = nf * 16 + (l & 15);
            int base = p * 128 + ((l >> 4) * 16);
            int xorr = (p & 7) << 4;
            bf16x8 bv0 = *(const bf16x8*)(buf + ((base)      ^ xorr));
            bf16x8 bv1 = *(const bf16x8*)(buf + ((base + 64) ^ xorr));
            acc[nf] = __builtin_amdgcn_mfma_f32_16x16x32_bf16(a0, bv0, acc[nf], 0, 0, 0);
            acc[nf] = __builtin_amdgcn_mfma_f32_16x16x32_bf16(a1, bv1, acc[nf], 0, 0, 0);
        }
    }

    // --- epilogue: bias + relu; D map col=lane&15, row=(lane>>4)*4+reg ---
#pragma unroll
    for (int nf = 0; nf < 4; nf++) {
#pragma unroll
        for (int rr = 0; rr < 4; rr++) {
            int o = g * 16 + (l >> 4) * 4 + rr;
            int p = nf * 16 + (l & 15);
            float v = acc[nf][rr] + bias[o];
            out[((n * COUT + o) * HH + ho) * WW + wx * 64 + p] = fmaxf(v, 0.f);
        }
    }
}

// ---------------------------------------------------------------------------
extern "C" void kernel_launch(void* const* d_in, const int* in_sizes, int n_in,
                              void* d_out, int out_size, void* d_ws, size_t ws_size,
                              hipStream_t stream) {
    const float* x     = (const float*)d_in[0];
    const float* w_off = (const float*)d_in[1];
    const float* b_off = (const float*)d_in[2];
    const float* w_mod = (const float*)d_in[3];
    const float* b_mod = (const float*)d_in[4];
    const float* w     = (const float*)d_in[5];
    const float* b     = (const float*)d_in[6];
    float* out = (float*)d_out;

    // ws layout: offmod f32[4*27*HW] | waux f32[576*28] | wfrag bf16[36864] | xh bf16[4*64*HW]
    float* offmod = (float*)d_ws;
    float* waux   = offmod + NB * 27 * HW;
    __hip_bfloat16* wfrag = (__hip_bfloat16*)(waux + 576 * 28);
    unsigned short* xh = (unsigned short*)(wfrag + 36864);
    // aux partials live in d_out (2*4*27*HW*4B = 33.2MB <= 37.7MB), fully
    // overwritten by dcn_main afterwards.
    float* part = out;

    to_bf16<<<dim3(4608), dim3(256), 0, stream>>>(x, xh);
    prep_weights<<<dim3(144), dim3(256), 0, stream>>>(w, w_off, w_mod, wfrag, waux);
    aux_part<<<dim3(768, 2), dim3(192), 0, stream>>>(xh, waux, part);
    aux_combine<<<dim3(3888), dim3(256), 0, stream>>>(part, b_off, b_mod, offmod);
    dcn_main<<<dim3(2304), dim3(256), 0, stream>>>(xh, wfrag, b, offmod, out);
}

// Round 4
// 144.216 us; speedup vs baseline: 2.2982x; 2.2982x over previous
//
#include <hip/hip_runtime.h>
#include <hip/hip_bf16.h>
#include <math.h>

// DCNv2 forward: offset/mod conv -> bilinear deform sample (NHWC bf16) ->
// main conv (bf16 MFMA) -> bias + relu.
// x [4,64,192,192] f32; w_off [18,64,3,3]; b_off[18]; w_mod [9,64,3,3]; b_mod[9];
// w [64,64,3,3]; b[64]; out [4,64,192,192] f32.

#define NB   4
#define CIN  64
#define COUT 64
#define HH   192
#define WW   192
#define HW   (HH*WW)

typedef __attribute__((ext_vector_type(4))) float f32x4;
typedef __attribute__((ext_vector_type(8))) short bf16x8;
typedef __attribute__((ext_vector_type(4))) unsigned int u32x4;

__device__ __forceinline__ int iclamp(int v, int lo, int hi) {
    return v < lo ? lo : (v > hi ? hi : v);
}
__device__ __forceinline__ unsigned short bf16bits(float f) {
    __hip_bfloat16 h = __float2bfloat16(f);
    return *reinterpret_cast<unsigned short*>(&h);
}
__device__ __forceinline__ float b2f(unsigned short u) {
    union { unsigned int i; float f; } t;
    t.i = ((unsigned int)u) << 16;
    return t.f;
}

// ---------------------------------------------------------------------------
// Kernel A: x f32 NCHW -> xt bf16 NHWC. One thread per pixel; 64 coalesced
// channel reads (stride HW across lanes = contiguous), pack 128 B, 8 b128
// stores per thread.
// ---------------------------------------------------------------------------
__global__ __launch_bounds__(256) void to_nhwc(
        const float* __restrict__ x, unsigned short* __restrict__ xt) {
    int n  = blockIdx.y;
    int px = blockIdx.x * 256 + threadIdx.x;     // 0..HW-1
    const float* xn = x + (size_t)n * CIN * HW + px;
    union { unsigned short us[64]; u32x4 q[8]; } pk;
#pragma unroll
    for (int c = 0; c < 64; c++) pk.us[c] = bf16bits(xn[c * HW]);
    u32x4* dst = (u32x4*)(xt + ((size_t)n * HW + px) * 64);
#pragma unroll
    for (int i = 0; i < 8; i++) dst[i] = pk.q[i];
}

// ---------------------------------------------------------------------------
// Kernel 0: weight repack (wfrag = main weights in MFMA A-frag order, bf16;
// waux[r=c*9+kk][28] = 27 aux out-channels contiguous).
// ---------------------------------------------------------------------------
__global__ __launch_bounds__(256) void prep_weights(
        const float* __restrict__ w, const float* __restrict__ w_off,
        const float* __restrict__ w_mod, __hip_bfloat16* __restrict__ wfrag,
        float* __restrict__ waux) {
    int idx = blockIdx.x * 256 + threadIdx.x;
    if (idx < 36864) {
        int j    = idx & 7;
        int lane = (idx >> 3) & 63;
        int kc   = (idx >> 9) & 1;
        int g    = (idx >> 10) & 3;
        int k    = idx >> 12;
        int o = g * 16 + (lane & 15);
        int c = kc * 32 + (lane >> 4) * 8 + j;
        wfrag[idx] = __float2bfloat16(w[(o * 64 + c) * 9 + k]);
    }
    if (idx < 576 * 28) {
        int r = idx / 28, j = idx % 28;
        float v = 0.f;
        if (j < 18)      v = w_off[j * 576 + r];
        else if (j < 27) v = w_mod[(j - 18) * 576 + r];
        waux[idx] = v;
    }
}

// ---------------------------------------------------------------------------
// Kernel 1a: aux conv partial — half the input channels (h = blockIdx.y).
// Reads f32 x (NCHW). part[h][n][j][HW] = 32-channel partial sums (no bias).
// ---------------------------------------------------------------------------
__global__ __launch_bounds__(192) void aux_part(
        const float* __restrict__ x, const float* __restrict__ waux,
        float* __restrict__ part) {
    int id = blockIdx.x;                       // 0..767
    int h  = blockIdx.y;                       // 0..1 channel half
    int sw = (id & 7) * 96 + (id >> 3);        // bijective XCD swizzle
    int n  = sw / HH;
    int ho = sw % HH;
    int wo = threadIdx.x;

    float acc[27];
#pragma unroll
    for (int j = 0; j < 27; j++) acc[j] = 0.f;

    const float* xn = x + ((size_t)n * CIN + h * 32) * HW;
    for (int c = 0; c < 32; c++) {
        const float* xc = xn + c * HW;
        int ci = h * 32 + c;
#pragma unroll
        for (int ky = 0; ky < 3; ky++) {
            int ys = ho + ky - 1;
            if ((unsigned)ys >= (unsigned)HH) continue;
#pragma unroll
            for (int kx = 0; kx < 3; kx++) {
                int xs = wo + kx - 1;
                float xv = ((unsigned)xs < (unsigned)WW) ? xc[ys * WW + xs] : 0.f;
                const float* wp = waux + (ci * 9 + ky * 3 + kx) * 28;  // uniform
#pragma unroll
                for (int j = 0; j < 27; j++)
                    acc[j] = fmaf(wp[j], xv, acc[j]);
            }
        }
    }

    float* pp = part + (((h * NB + n) * 27) * HH + ho) * WW + wo;
#pragma unroll
    for (int j = 0; j < 27; j++) pp[j * HW] = acc[j];
}

// ---------------------------------------------------------------------------
// Kernel 1b: combine halves + bias; ch<18 raw offsets, ch>=18 2*sigmoid.
// ---------------------------------------------------------------------------
__global__ __launch_bounds__(256) void aux_combine(
        const float* __restrict__ part, const float* __restrict__ b_off,
        const float* __restrict__ b_mod, float* __restrict__ offmod) {
    int t = blockIdx.x * 256 + threadIdx.x;
    int e = t * 4;
    int n   = e / (27 * HW);
    int r   = e % (27 * HW);
    int j   = r / HW;
    int pix = r % HW;
    f32x4 p0 = *(const f32x4*)(part + ((n * 27 + j) * HW + pix));
    f32x4 p1 = *(const f32x4*)(part + (((NB + n) * 27 + j) * HW + pix));
    float bb = (j < 18) ? b_off[j] : b_mod[j - 18];
    f32x4 s = p0 + p1;
    f32x4 o;
#pragma unroll
    for (int i = 0; i < 4; i++) {
        float v = s[i] + bb;
        o[i] = (j < 18) ? v : 2.f / (1.f + expf(-v));
    }
    *(f32x4*)(offmod + (n * 27 + j) * HW + pix) = o;
}

// ---------------------------------------------------------------------------
// Kernel 2: deformable sampling (NHWC bf16) + bf16-MFMA main conv + bias+relu.
// Block = 4 waves, tile = 64 px (one ho row segment).
// offmod for the tile staged in LDS once. Per tap: lane = (pixel, 8-ch chunk);
// 4 corner b128 loads per lane per half (2 halves of 8 px), bilinear combine,
// swizzled LDS write; barrier; 8 MFMA per wave (16 out-ch x 64 px).
// ---------------------------------------------------------------------------
__global__ __launch_bounds__(256, 4) void dcn_main(
        const unsigned short* __restrict__ xt,
        const __hip_bfloat16* __restrict__ wfrag,
        const float* __restrict__ bias, const float* __restrict__ offmod,
        float* __restrict__ out) {
    __shared__ __align__(16) char lds[2][64 * 128];  // val[p][c], double-buffered
    __shared__ float oml[27][64];                    // offsets/mod for the tile

    int tid = threadIdx.x;
    int l   = tid & 63;
    int g   = __builtin_amdgcn_readfirstlane(tid >> 6);

    int id = blockIdx.x;                        // 0..2303
    int sw = (id & 7) * 288 + (id >> 3);        // bijective XCD swizzle
    int n  = sw / 576;
    int r  = sw % 576;
    int ho = r / 3;
    int wx = r % 3;

    // stage this tile's offsets/modulation (27 ch x 64 px) into LDS
    {
        const float* omp = offmod + ((size_t)n * 27 * HH + ho) * WW + wx * 64 + l;
#pragma unroll
        for (int j4 = 0; j4 < 7; j4++) {
            int jj = j4 * 4 + g;
            if (jj < 27) oml[jj][l] = omp[jj * HW];
        }
    }

    const char* xb = (const char*)xt + (size_t)n * HW * 128;

    f32x4 acc[4];
#pragma unroll
    for (int nf = 0; nf < 4; nf++) acc[nf] = (f32x4){0.f, 0.f, 0.f, 0.f};

    int ch = l & 7;        // 8-channel chunk (16 B)
    int pr = l >> 3;       // pixel-in-group 0..7
    int cb = ch * 16;

    __syncthreads();

#pragma unroll 1
    for (int k = 0; k < 9; k++) {
        // A fragments for this tap (L2-hot, coalesced 16 B/lane)
        const bf16x8* wf = ((const bf16x8*)wfrag) + ((k * 4 + g) * 2) * 64 + l;
        bf16x8 a0 = wf[0];
        bf16x8 a1 = wf[64];

        int ky = k / 3, kx = k - 3 * (k / 3);
        char* buf = lds[k & 1];

        bf16x8 q[2][4];
        float wt4[2][4];
        // phase 1: addresses + issue all 8 corner loads (both pixel halves)
#pragma unroll
        for (int it = 0; it < 2; it++) {
            int p = g * 16 + it * 8 + pr;
            float offy = oml[2 * k][p];
            float offx = oml[2 * k + 1][p];
            float mm   = oml[18 + k][p];
            float py  = offy + (float)(ho - 1 + ky);
            float pxf = offx + (float)(wx * 64 + p - 1 + kx);
            float y0f = floorf(py), x0f = floorf(pxf);
            float ly = py - y0f, lx = pxf - x0f;
            int y0 = (int)y0f, x0 = (int)x0f;
            int y1 = y0 + 1, x1 = x0 + 1;
            bool y0ok = (unsigned)y0 < (unsigned)HH, y1ok = (unsigned)y1 < (unsigned)HH;
            bool x0ok = (unsigned)x0 < (unsigned)WW, x1ok = (unsigned)x1 < (unsigned)WW;
            wt4[it][0] = (y0ok && x0ok) ? mm * (1.f - ly) * (1.f - lx) : 0.f;
            wt4[it][1] = (y0ok && x1ok) ? mm * (1.f - ly) * lx         : 0.f;
            wt4[it][2] = (y1ok && x0ok) ? mm * ly * (1.f - lx)         : 0.f;
            wt4[it][3] = (y1ok && x1ok) ? mm * ly * lx                 : 0.f;
            int y0c = iclamp(y0, 0, HH - 1), y1c = iclamp(y1, 0, HH - 1);
            int x0c = iclamp(x0, 0, WW - 1), x1c = iclamp(x1, 0, WW - 1);
            q[it][0] = *(const bf16x8*)(xb + (y0c * WW + x0c) * 128 + cb);
            q[it][1] = *(const bf16x8*)(xb + (y0c * WW + x1c) * 128 + cb);
            q[it][2] = *(const bf16x8*)(xb + (y1c * WW + x0c) * 128 + cb);
            q[it][3] = *(const bf16x8*)(xb + (y1c * WW + x1c) * 128 + cb);
        }
        // phase 2: bilinear combine + pack + swizzled LDS write
#pragma unroll
        for (int it = 0; it < 2; it++) {
            int p = g * 16 + it * 8 + pr;
            union { unsigned short us[8]; u32x4 v; } pk;
#pragma unroll
            for (int j = 0; j < 8; j++) {
                float v = b2f((unsigned short)q[it][0][j]) * wt4[it][0];
                v = fmaf(b2f((unsigned short)q[it][1][j]), wt4[it][1], v);
                v = fmaf(b2f((unsigned short)q[it][2][j]), wt4[it][2], v);
                v = fmaf(b2f((unsigned short)q[it][3][j]), wt4[it][3], v);
                pk.us[j] = bf16bits(v);
            }
            *(u32x4*)(buf + ((p * 128 + cb) ^ (pr << 4))) = pk.v;
        }

        __syncthreads();

        // 8 MFMA: D[o=16g..][p] += A(16x32) * V(32x64)
#pragma unroll
        for (int nf = 0; nf < 4; nf++) {
            int p = nf * 16 + (l & 15);
            int base = p * 128 + ((l >> 4) * 16);
            int xorr = (p & 7) << 4;
            bf16x8 bv0 = *(const bf16x8*)(buf + ((base)      ^ xorr));
            bf16x8 bv1 = *(const bf16x8*)(buf + ((base + 64) ^ xorr));
            acc[nf] = __builtin_amdgcn_mfma_f32_16x16x32_bf16(a0, bv0, acc[nf], 0, 0, 0);
            acc[nf] = __builtin_amdgcn_mfma_f32_16x16x32_bf16(a1, bv1, acc[nf], 0, 0, 0);
        }
    }

    // epilogue: bias + relu; D map col=lane&15, row=(lane>>4)*4+reg
#pragma unroll
    for (int nf = 0; nf < 4; nf++) {
#pragma unroll
        for (int rr = 0; rr < 4; rr++) {
            int o = g * 16 + (l >> 4) * 4 + rr;
            int p = nf * 16 + (l & 15);
            float v = acc[nf][rr] + bias[o];
            out[(((size_t)n * COUT + o) * HH + ho) * WW + wx * 64 + p] = fmaxf(v, 0.f);
        }
    }
}

// ---------------------------------------------------------------------------
extern "C" void kernel_launch(void* const* d_in, const int* in_sizes, int n_in,
                              void* d_out, int out_size, void* d_ws, size_t ws_size,
                              hipStream_t stream) {
    const float* x     = (const float*)d_in[0];
    const float* w_off = (const float*)d_in[1];
    const float* b_off = (const float*)d_in[2];
    const float* w_mod = (const float*)d_in[3];
    const float* b_mod = (const float*)d_in[4];
    const float* w     = (const float*)d_in[5];
    const float* b     = (const float*)d_in[6];
    float* out = (float*)d_out;

    // ws layout: offmod f32[4*27*HW] | waux f32[576*28] | wfrag bf16[36864] |
    //            xt bf16 NHWC [4*HW*64]   (total ~34.9 MB, same as rounds 2-3)
    float* offmod = (float*)d_ws;
    float* waux   = offmod + NB * 27 * HW;
    __hip_bfloat16* wfrag = (__hip_bfloat16*)(waux + 576 * 28);
    unsigned short* xt = (unsigned short*)(wfrag + 36864);
    // aux partials live in d_out (33.2 MB <= 37.7 MB), fully overwritten later
    float* part = out;

    to_nhwc<<<dim3(144, NB), dim3(256), 0, stream>>>(x, xt);
    prep_weights<<<dim3(144), dim3(256), 0, stream>>>(w, w_off, w_mod, wfrag, waux);
    aux_part<<<dim3(768, 2), dim3(192), 0, stream>>>(x, waux, part);
    aux_combine<<<dim3(3888), dim3(256), 0, stream>>>(part, b_off, b_mod, offmod);
    dcn_main<<<dim3(2304), dim3(256), 0, stream>>>(xt, wfrag, b, offmod, out);
}

// Round 5
// 106.551 us; speedup vs baseline: 3.1106x; 1.3535x over previous
//
#include <hip/hip_runtime.h>
#include <hip/hip_bf16.h>
#include <math.h>

// DCNv2 forward, all-MFMA: aux conv (offsets+mod) and main deformable conv
// both run as bf16 MFMA over an NHWC bf16 copy of x.
// x [4,64,192,192] f32; w_off [18,64,3,3]; b_off[18]; w_mod [9,64,3,3]; b_mod[9];
// w [64,64,3,3]; b[64]; out [4,64,192,192] f32.

#define NB   4
#define CIN  64
#define COUT 64
#define HH   192
#define WW   192
#define HW   (HH*WW)

typedef __attribute__((ext_vector_type(4))) float f32x4;
typedef __attribute__((ext_vector_type(8))) short bf16x8;
typedef __attribute__((ext_vector_type(4))) unsigned int u32x4;

__device__ __forceinline__ int iclamp(int v, int lo, int hi) {
    return v < lo ? lo : (v > hi ? hi : v);
}
__device__ __forceinline__ unsigned short bf16bits(float f) {
    __hip_bfloat16 h = __float2bfloat16(f);
    return *reinterpret_cast<unsigned short*>(&h);
}
__device__ __forceinline__ float b2f(unsigned short u) {
    union { unsigned int i; float f; } t;
    t.i = ((unsigned int)u) << 16;
    return t.f;
}

// ---------------------------------------------------------------------------
// Kernel A: x f32 NCHW -> xt bf16 NHWC (128 B per pixel).
// ---------------------------------------------------------------------------
__global__ __launch_bounds__(256) void to_nhwc(
        const float* __restrict__ x, unsigned short* __restrict__ xt) {
    int n  = blockIdx.y;
    int px = blockIdx.x * 256 + threadIdx.x;     // 0..HW-1
    const float* xn = x + (size_t)n * CIN * HW + px;
    union { unsigned short us[64]; u32x4 q[8]; } pk;
#pragma unroll
    for (int c = 0; c < 64; c++) pk.us[c] = bf16bits(xn[c * HW]);
    u32x4* dst = (u32x4*)(xt + ((size_t)n * HW + px) * 64);
#pragma unroll
    for (int i = 0; i < 8; i++) dst[i] = pk.q[i];
}

// ---------------------------------------------------------------------------
// Kernel 0: weight repack into MFMA A-fragment order (bf16).
//  wfrag  (main, 64 out-ch): idx = (((k*4+g)*2+kc)*64 + l)*8 + j
//         o = g*16 + (l&15); c = kc*32 + (l>>4)*8 + j
//  wauxf  (aux, 32 out-ch padded from 27): idx = (((k*2+g)*2+kc)*64 + l)*8 + j
//         o<18: w_off, o<27: w_mod, else 0
//  baux   f32[32]: b_off | b_mod | 0
// ---------------------------------------------------------------------------
__global__ __launch_bounds__(256) void prep_weights(
        const float* __restrict__ w, const float* __restrict__ w_off,
        const float* __restrict__ w_mod, const float* __restrict__ b_off,
        const float* __restrict__ b_mod, __hip_bfloat16* __restrict__ wfrag,
        __hip_bfloat16* __restrict__ wauxf, float* __restrict__ baux) {
    int idx = blockIdx.x * 256 + threadIdx.x;
    if (idx < 36864) {
        int j    = idx & 7;
        int lane = (idx >> 3) & 63;
        int kc   = (idx >> 9) & 1;
        int g    = (idx >> 10) & 3;
        int k    = idx >> 12;
        int o = g * 16 + (lane & 15);
        int c = kc * 32 + (lane >> 4) * 8 + j;
        wfrag[idx] = __float2bfloat16(w[(o * 64 + c) * 9 + k]);
    }
    if (idx < 18432) {
        int j    = idx & 7;
        int lane = (idx >> 3) & 63;
        int kc   = (idx >> 9) & 1;
        int g    = (idx >> 10) & 1;
        int k    = idx >> 11;
        int o = g * 16 + (lane & 15);
        int c = kc * 32 + (lane >> 4) * 8 + j;
        float v = 0.f;
        if (o < 18)      v = w_off[(o * 64 + c) * 9 + k];
        else if (o < 27) v = w_mod[((o - 18) * 64 + c) * 9 + k];
        wauxf[idx] = __float2bfloat16(v);
    }
    if (idx < 32) {
        float v = 0.f;
        if (idx < 18)      v = b_off[idx];
        else if (idx < 27) v = b_mod[idx - 18];
        baux[idx] = v;
    }
}

// ---------------------------------------------------------------------------
// Kernel 1: aux conv via MFMA. Block = 2 waves; tile = 64 px (one ho, wx).
// Wave g computes out-ch [16g,16g+16) x 64 px. Per tap: B-fragments are
// DIRECT global 16 B loads from NHWC xt at the shifted pixel (no LDS, no
// im2col); rows out of range skip the tap, columns out of range zero the
// fragment. Epilogue: bias, 2*sigmoid on mod channels, bf16 pixel-major
// store offmod[n][pix][32].
// ---------------------------------------------------------------------------
__global__ __launch_bounds__(128) void aux_mfma(
        const unsigned short* __restrict__ xt,
        const __hip_bfloat16* __restrict__ wauxf,
        const float* __restrict__ baux,
        unsigned short* __restrict__ offmod) {
    int tid = threadIdx.x;
    int l   = tid & 63;
    int g   = __builtin_amdgcn_readfirstlane(tid >> 6);   // 0..1

    int id = blockIdx.x;                        // 0..2303
    int sw = (id & 7) * 288 + (id >> 3);        // bijective XCD swizzle
    int n  = sw / 576;
    int r  = sw % 576;
    int ho = r / 3;
    int wx = r % 3;
    int wobase = wx * 64;

    const char* xb = (const char*)xt + (size_t)n * HW * 128;

    f32x4 acc[4];
#pragma unroll
    for (int nf = 0; nf < 4; nf++) acc[nf] = (f32x4){0.f, 0.f, 0.f, 0.f};

    const bf16x8 zero8 = (bf16x8){0, 0, 0, 0, 0, 0, 0, 0};
    int cb = (l >> 4) * 16;                     // kc-chunk byte offset in pixel

#pragma unroll 1
    for (int k = 0; k < 9; k++) {
        int ky = k / 3, kx = k - 3 * (k / 3);
        int ys = ho + ky - 1;
        if ((unsigned)ys >= (unsigned)HH) continue;   // uniform: zero row

        const bf16x8* wf = ((const bf16x8*)wauxf) + ((k * 2 + g) * 2) * 64 + l;
        bf16x8 a0 = wf[0];
        bf16x8 a1 = wf[64];
        const char* xrow = xb + (size_t)ys * WW * 128;

#pragma unroll
        for (int nf = 0; nf < 4; nf++) {
            int p  = nf * 16 + (l & 15);
            int xs = wobase + p + kx - 1;
            bool ok = (unsigned)xs < (unsigned)WW;
            int xsc = iclamp(xs, 0, WW - 1);
            const char* pp = xrow + xsc * 128 + cb;
            bf16x8 bv0 = *(const bf16x8*)(pp);
            bf16x8 bv1 = *(const bf16x8*)(pp + 64);
            if (!ok) { bv0 = zero8; bv1 = zero8; }
            acc[nf] = __builtin_amdgcn_mfma_f32_16x16x32_bf16(a0, bv0, acc[nf], 0, 0, 0);
            acc[nf] = __builtin_amdgcn_mfma_f32_16x16x32_bf16(a1, bv1, acc[nf], 0, 0, 0);
        }
    }

    // epilogue: D map col=lane&15 (pixel), row=(lane>>4)*4+rr (out-ch j)
    size_t pixbase = (size_t)n * HW + (size_t)ho * WW + wobase;
#pragma unroll
    for (int nf = 0; nf < 4; nf++) {
        int p = nf * 16 + (l & 15);
        unsigned short* op = offmod + (pixbase + p) * 32;
#pragma unroll
        for (int rp = 0; rp < 2; rp++) {        // pairs (rr, rr+1) -> one u32
            int j0 = g * 16 + (l >> 4) * 4 + rp * 2;
            float v0 = acc[nf][rp * 2]     + baux[j0];
            float v1 = acc[nf][rp * 2 + 1] + baux[j0 + 1];
            if (j0 >= 18)     v0 = 2.f / (1.f + expf(-v0));
            if (j0 + 1 >= 18) v1 = 2.f / (1.f + expf(-v1));
            unsigned int pk = (unsigned int)bf16bits(v0)
                            | ((unsigned int)bf16bits(v1) << 16);
            *(unsigned int*)(op + j0) = pk;
        }
    }
}

// ---------------------------------------------------------------------------
// Kernel 2: deformable sampling (NHWC bf16) + bf16-MFMA main conv + bias+relu.
// Block = 4 waves, tile = 64 px. offmod (pixel-major bf16) staged to LDS once.
// Per tap: lane = (pixel, 8-ch chunk); 4 corner b128 loads, bilinear combine,
// swizzled LDS write; barrier; 8 MFMA per wave.
// ---------------------------------------------------------------------------
__global__ __launch_bounds__(256, 4) void dcn_main(
        const unsigned short* __restrict__ xt,
        const __hip_bfloat16* __restrict__ wfrag,
        const float* __restrict__ bias,
        const unsigned short* __restrict__ offmod,
        float* __restrict__ out) {
    __shared__ __align__(16) char lds[2][64 * 128];  // val[p][c], double-buffered
    __shared__ float oml[32][64];                    // offsets/mod for the tile

    int tid = threadIdx.x;
    int l   = tid & 63;
    int g   = __builtin_amdgcn_readfirstlane(tid >> 6);

    int id = blockIdx.x;                        // 0..2303
    int sw = (id & 7) * 288 + (id >> 3);        // bijective XCD swizzle
    int n  = sw / 576;
    int r  = sw % 576;
    int ho = r / 3;
    int wx = r % 3;

    // stage this tile's offsets/mod: lane l = pixel, wave g = 8-ch chunk
    {
        const unsigned short* omp = offmod
            + ((size_t)n * HW + (size_t)ho * WW + wx * 64 + l) * 32 + g * 8;
        union { unsigned short us[8]; u32x4 q; } t;
        t.q = *(const u32x4*)omp;
#pragma unroll
        for (int i = 0; i < 8; i++) oml[g * 8 + i][l] = b2f(t.us[i]);
    }

    const char* xb = (const char*)xt + (size_t)n * HW * 128;

    f32x4 acc[4];
#pragma unroll
    for (int nf = 0; nf < 4; nf++) acc[nf] = (f32x4){0.f, 0.f, 0.f, 0.f};

    int ch = l & 7;        // 8-channel chunk (16 B)
    int pr = l >> 3;       // pixel-in-group 0..7
    int cb = ch * 16;

    __syncthreads();

#pragma unroll 1
    for (int k = 0; k < 9; k++) {
        const bf16x8* wf = ((const bf16x8*)wfrag) + ((k * 4 + g) * 2) * 64 + l;
        bf16x8 a0 = wf[0];
        bf16x8 a1 = wf[64];

        int ky = k / 3, kx = k - 3 * (k / 3);
        char* buf = lds[k & 1];

        bf16x8 q[2][4];
        float wt4[2][4];
#pragma unroll
        for (int it = 0; it < 2; it++) {
            int p = g * 16 + it * 8 + pr;
            float offy = oml[2 * k][p];
            float offx = oml[2 * k + 1][p];
            float mm   = oml[18 + k][p];
            float py  = offy + (float)(ho - 1 + ky);
            float pxf = offx + (float)(wx * 64 + p - 1 + kx);
            float y0f = floorf(py), x0f = floorf(pxf);
            float ly = py - y0f, lx = pxf - x0f;
            int y0 = (int)y0f, x0 = (int)x0f;
            int y1 = y0 + 1, x1 = x0 + 1;
            bool y0ok = (unsigned)y0 < (unsigned)HH, y1ok = (unsigned)y1 < (unsigned)HH;
            bool x0ok = (unsigned)x0 < (unsigned)WW, x1ok = (unsigned)x1 < (unsigned)WW;
            wt4[it][0] = (y0ok && x0ok) ? mm * (1.f - ly) * (1.f - lx) : 0.f;
            wt4[it][1] = (y0ok && x1ok) ? mm * (1.f - ly) * lx         : 0.f;
            wt4[it][2] = (y1ok && x0ok) ? mm * ly * (1.f - lx)         : 0.f;
            wt4[it][3] = (y1ok && x1ok) ? mm * ly * lx                 : 0.f;
            int y0c = iclamp(y0, 0, HH - 1), y1c = iclamp(y1, 0, HH - 1);
            int x0c = iclamp(x0, 0, WW - 1), x1c = iclamp(x1, 0, WW - 1);
            q[it][0] = *(const bf16x8*)(xb + (y0c * WW + x0c) * 128 + cb);
            q[it][1] = *(const bf16x8*)(xb + (y0c * WW + x1c) * 128 + cb);
            q[it][2] = *(const bf16x8*)(xb + (y1c * WW + x0c) * 128 + cb);
            q[it][3] = *(const bf16x8*)(xb + (y1c * WW + x1c) * 128 + cb);
        }
#pragma unroll
        for (int it = 0; it < 2; it++) {
            int p = g * 16 + it * 8 + pr;
            union { unsigned short us[8]; u32x4 v; } pk;
#pragma unroll
            for (int j = 0; j < 8; j++) {
                float v = b2f((unsigned short)q[it][0][j]) * wt4[it][0];
                v = fmaf(b2f((unsigned short)q[it][1][j]), wt4[it][1], v);
                v = fmaf(b2f((unsigned short)q[it][2][j]), wt4[it][2], v);
                v = fmaf(b2f((unsigned short)q[it][3][j]), wt4[it][3], v);
                pk.us[j] = bf16bits(v);
            }
            *(u32x4*)(buf + ((p * 128 + cb) ^ (pr << 4))) = pk.v;
        }

        __syncthreads();

#pragma unroll
        for (int nf = 0; nf < 4; nf++) {
            int p = nf * 16 + (l & 15);
            int base = p * 128 + ((l >> 4) * 16);
            int xorr = (p & 7) << 4;
            bf16x8 bv0 = *(const bf16x8*)(buf + ((base)      ^ xorr));
            bf16x8 bv1 = *(const bf16x8*)(buf + ((base + 64) ^ xorr));
            acc[nf] = __builtin_amdgcn_mfma_f32_16x16x32_bf16(a0, bv0, acc[nf], 0, 0, 0);
            acc[nf] = __builtin_amdgcn_mfma_f32_16x16x32_bf16(a1, bv1, acc[nf], 0, 0, 0);
        }
    }

    // epilogue: bias + relu; D map col=lane&15, row=(lane>>4)*4+reg
#pragma unroll
    for (int nf = 0; nf < 4; nf++) {
#pragma unroll
        for (int rr = 0; rr < 4; rr++) {
            int o = g * 16 + (l >> 4) * 4 + rr;
            int p = nf * 16 + (l & 15);
            float v = acc[nf][rr] + bias[o];
            out[(((size_t)n * COUT + o) * HH + ho) * WW + wx * 64 + p] = fmaxf(v, 0.f);
        }
    }
}

// ---------------------------------------------------------------------------
extern "C" void kernel_launch(void* const* d_in, const int* in_sizes, int n_in,
                              void* d_out, int out_size, void* d_ws, size_t ws_size,
                              hipStream_t stream) {
    const float* x     = (const float*)d_in[0];
    const float* w_off = (const float*)d_in[1];
    const float* b_off = (const float*)d_in[2];
    const float* w_mod = (const float*)d_in[3];
    const float* b_mod = (const float*)d_in[4];
    const float* w     = (const float*)d_in[5];
    const float* b     = (const float*)d_in[6];
    float* out = (float*)d_out;

    // ws layout (bytes):
    //  wfrag bf16[36864] | wauxf bf16[18432] | baux f32[32] |
    //  xt bf16 NHWC [4*HW*64] | offmod bf16 pixel-major [4*HW*32]   (~28.4 MB)
    __hip_bfloat16* wfrag = (__hip_bfloat16*)d_ws;
    __hip_bfloat16* wauxf = wfrag + 36864;
    float* baux = (float*)(wauxf + 18432);
    unsigned short* xt = (unsigned short*)(baux + 32);
    unsigned short* offmod = xt + (size_t)NB * HW * 64;

    to_nhwc<<<dim3(144, NB), dim3(256), 0, stream>>>(x, xt);
    prep_weights<<<dim3(144), dim3(256), 0, stream>>>(w, w_off, w_mod, b_off,
                                                      b_mod, wfrag, wauxf, baux);
    aux_mfma<<<dim3(2304), dim3(128), 0, stream>>>(xt, wauxf, baux, offmod);
    dcn_main<<<dim3(2304), dim3(256), 0, stream>>>(xt, wfrag, b, offmod, out);
}

// Round 6
// 86.997 us; speedup vs baseline: 3.8097x; 1.2248x over previous
//
#include <hip/hip_runtime.h>
#include <hip/hip_bf16.h>
#include <math.h>

// DCNv2 forward, fully fused: one kernel computes the offset/mod conv (bf16
// MFMA, results kept in LDS), deformable bilinear sampling (packed f32), and
// the main conv (bf16 MFMA) + bias + relu. Input staged once as NHWC bf16.
// x [4,64,192,192] f32; w_off [18,64,3,3]; b_off[18]; w_mod [9,64,3,3]; b_mod[9];
// w [64,64,3,3]; b[64]; out [4,64,192,192] f32.

#define NB   4
#define CIN  64
#define COUT 64
#define HH   192
#define WW   192
#define HW   (HH*WW)

typedef __attribute__((ext_vector_type(4))) float f32x4;
typedef __attribute__((ext_vector_type(2))) float f32x2;
typedef __attribute__((ext_vector_type(8))) short bf16x8;
typedef __attribute__((ext_vector_type(4))) unsigned int u32x4;

__device__ __forceinline__ int iclamp(int v, int lo, int hi) {
    return v < lo ? lo : (v > hi ? hi : v);
}
__device__ __forceinline__ unsigned short bf16bits(float f) {
    __hip_bfloat16 h = __float2bfloat16(f);
    return *reinterpret_cast<unsigned short*>(&h);
}
__device__ __forceinline__ float b2f(unsigned short u) {
    union { unsigned int i; float f; } t;
    t.i = ((unsigned int)u) << 16;
    return t.f;
}
// unpack a u32 holding 2 bf16 into float2: lo = u<<16, hi = u & 0xffff0000
__device__ __forceinline__ f32x2 unpk2(unsigned int u) {
    union { unsigned int i; float f; } lo, hi;
    lo.i = u << 16;
    hi.i = u & 0xffff0000u;
    return (f32x2){lo.f, hi.f};
}
#if __has_builtin(__builtin_elementwise_fma)
__device__ __forceinline__ f32x2 pfma(f32x2 a, f32x2 b, f32x2 c) {
    return __builtin_elementwise_fma(a, b, c);
}
#else
__device__ __forceinline__ f32x2 pfma(f32x2 a, f32x2 b, f32x2 c) {
    return (f32x2){fmaf(a.x, b.x, c.x), fmaf(a.y, b.y, c.y)};
}
#endif

// ---------------------------------------------------------------------------
// Kernel A: x f32 NCHW -> xt bf16 NHWC (128 B per pixel).
// ---------------------------------------------------------------------------
__global__ __launch_bounds__(256) void to_nhwc(
        const float* __restrict__ x, unsigned short* __restrict__ xt) {
    int n  = blockIdx.y;
    int px = blockIdx.x * 256 + threadIdx.x;     // 0..HW-1
    const float* xn = x + (size_t)n * CIN * HW + px;
    union { unsigned short us[64]; u32x4 q[8]; } pk;
#pragma unroll
    for (int c = 0; c < 64; c++) pk.us[c] = bf16bits(xn[c * HW]);
    u32x4* dst = (u32x4*)(xt + ((size_t)n * HW + px) * 64);
#pragma unroll
    for (int i = 0; i < 8; i++) dst[i] = pk.q[i];
}

// ---------------------------------------------------------------------------
// Kernel 0: weight repack into MFMA A-fragment order (bf16).
//  wfrag (main, 64 out-ch): idx = (((k*4+g)*2+kc)*64 + l)*8 + j
//        o = g*16 + (l&15); c = kc*32 + (l>>4)*8 + j
//  wauxf (aux, 32 out-ch padded from 27): idx = ((k*4 + ga*2 + kc)*64 + l)*8 + j
//        o = ga*16 + (l&15); o<18: w_off, o<27: w_mod, else 0
//  baux  f32[32]: b_off | b_mod | 0
// ---------------------------------------------------------------------------
__global__ __launch_bounds__(256) void prep_weights(
        const float* __restrict__ w, const float* __restrict__ w_off,
        const float* __restrict__ w_mod, const float* __restrict__ b_off,
        const float* __restrict__ b_mod, __hip_bfloat16* __restrict__ wfrag,
        __hip_bfloat16* __restrict__ wauxf, float* __restrict__ baux) {
    int idx = blockIdx.x * 256 + threadIdx.x;
    if (idx < 36864) {
        int j    = idx & 7;
        int lane = (idx >> 3) & 63;
        int kc   = (idx >> 9) & 1;
        int g    = (idx >> 10) & 3;
        int k    = idx >> 12;
        int o = g * 16 + (lane & 15);
        int c = kc * 32 + (lane >> 4) * 8 + j;
        wfrag[idx] = __float2bfloat16(w[(o * 64 + c) * 9 + k]);
    }
    if (idx < 18432) {
        int j    = idx & 7;
        int lane = (idx >> 3) & 63;
        int kc   = (idx >> 9) & 1;
        int ga   = (idx >> 10) & 1;
        int k    = idx >> 11;
        int o = ga * 16 + (lane & 15);
        int c = kc * 32 + (lane >> 4) * 8 + j;
        float v = 0.f;
        if (o < 18)      v = w_off[(o * 64 + c) * 9 + k];
        else if (o < 27) v = w_mod[((o - 18) * 64 + c) * 9 + k];
        wauxf[idx] = __float2bfloat16(v);
    }
    if (idx < 32) {
        float v = 0.f;
        if (idx < 18)      v = b_off[idx];
        else if (idx < 27) v = b_mod[idx - 18];
        baux[idx] = v;
    }
}

// ---------------------------------------------------------------------------
// Kernel 1 (fused): per 64-px tile:
//  Phase A — aux conv via MFMA: wave g computes all 32 aux channels for its
//    16 pixels (B = direct NHWC loads at shifted taps; 36 MFMA/wave), applies
//    bias + 2*sigmoid, writes oml[ch][px] in LDS.
//  Phase B — deformable sampling (packed-f32 bilinear) + main conv MFMA +
//    bias + relu (as round 5).
// ---------------------------------------------------------------------------
__global__ __launch_bounds__(256, 6) void dcn_fused(
        const unsigned short* __restrict__ xt,
        const __hip_bfloat16* __restrict__ wfrag,
        const __hip_bfloat16* __restrict__ wauxf,
        const float* __restrict__ baux,
        const float* __restrict__ bias,
        float* __restrict__ out) {
    __shared__ __align__(16) char lds[2][64 * 128];  // val[p][c], double-buffered
    __shared__ float oml[32][65];                    // aux results (stride 65: bank-safe)

    int tid = threadIdx.x;
    int l   = tid & 63;
    int g   = __builtin_amdgcn_readfirstlane(tid >> 6);

    int id = blockIdx.x;                        // 0..2303
    int sw = (id & 7) * 288 + (id >> 3);        // bijective XCD swizzle
    int n  = sw / 576;
    int r  = sw % 576;
    int ho = r / 3;
    int wx = r % 3;
    int wobase = wx * 64;

    const char* xb = (const char*)xt + (size_t)n * HW * 128;

    // ================= Phase A: aux conv for this tile =================
    {
        f32x4 aacc[2];
        aacc[0] = (f32x4){0.f, 0.f, 0.f, 0.f};
        aacc[1] = (f32x4){0.f, 0.f, 0.f, 0.f};
        const bf16x8 zero8 = (bf16x8){0, 0, 0, 0, 0, 0, 0, 0};
        int pa  = g * 16 + (l & 15);            // this lane's pixel
        int cba = (l >> 4) * 16;                // 8-ch chunk byte offset

#pragma unroll 1
        for (int k = 0; k < 9; k++) {
            int ky = k / 3, kx = k - 3 * (k / 3);
            int ys = ho + ky - 1;
            if ((unsigned)ys >= (unsigned)HH) continue;   // uniform row skip
            int xs = wobase + pa + kx - 1;
            bool ok = (unsigned)xs < (unsigned)WW;
            int xsc = iclamp(xs, 0, WW - 1);
            const char* pp = xb + ((size_t)ys * WW + xsc) * 128;
            const bf16x8* wa = ((const bf16x8*)wauxf) + (k * 4) * 64 + l;
#pragma unroll
            for (int kc = 0; kc < 2; kc++) {
                bf16x8 bv = *(const bf16x8*)(pp + kc * 64 + cba);
                if (!ok) bv = zero8;
                bf16x8 a0 = wa[(kc)     * 64];      // o 0..15
                bf16x8 a1 = wa[(2 + kc) * 64];      // o 16..31
                aacc[0] = __builtin_amdgcn_mfma_f32_16x16x32_bf16(a0, bv, aacc[0], 0, 0, 0);
                aacc[1] = __builtin_amdgcn_mfma_f32_16x16x32_bf16(a1, bv, aacc[1], 0, 0, 0);
            }
        }
        // epilogue: bias, 2*sigmoid on ch>=18, write LDS oml[ch][pa]
#pragma unroll
        for (int h = 0; h < 2; h++) {
#pragma unroll
            for (int rr = 0; rr < 4; rr++) {
                int o = h * 16 + (l >> 4) * 4 + rr;
                float v = aacc[h][rr] + baux[o];
                if (o >= 18) v = 2.f / (1.f + expf(-v));
                oml[o][pa] = v;
            }
        }
    }
    __syncthreads();

    // ================= Phase B: deform sample + main conv =================
    f32x4 acc[4];
#pragma unroll
    for (int nf = 0; nf < 4; nf++) acc[nf] = (f32x4){0.f, 0.f, 0.f, 0.f};

    int ch = l & 7;        // 8-channel chunk (16 B)
    int pr = l >> 3;       // pixel-in-group 0..7
    int cb = ch * 16;

#pragma unroll 1
    for (int k = 0; k < 9; k++) {
        const bf16x8* wf = ((const bf16x8*)wfrag) + ((k * 4 + g) * 2) * 64 + l;
        bf16x8 a0 = wf[0];
        bf16x8 a1 = wf[64];

        int ky = k / 3, kx = k - 3 * (k / 3);
        char* buf = lds[k & 1];

        u32x4 q[2][4];
        float wt4[2][4];
#pragma unroll
        for (int it = 0; it < 2; it++) {
            int p = g * 16 + it * 8 + pr;
            float offy = oml[2 * k][p];
            float offx = oml[2 * k + 1][p];
            float mm   = oml[18 + k][p];
            float py  = offy + (float)(ho - 1 + ky);
            float pxf = offx + (float)(wx * 64 + p - 1 + kx);
            float y0f = floorf(py), x0f = floorf(pxf);
            float ly = py - y0f, lx = pxf - x0f;
            int y0 = (int)y0f, x0 = (int)x0f;
            int y1 = y0 + 1, x1 = x0 + 1;
            bool y0ok = (unsigned)y0 < (unsigned)HH, y1ok = (unsigned)y1 < (unsigned)HH;
            bool x0ok = (unsigned)x0 < (unsigned)WW, x1ok = (unsigned)x1 < (unsigned)WW;
            wt4[it][0] = (y0ok && x0ok) ? mm * (1.f - ly) * (1.f - lx) : 0.f;
            wt4[it][1] = (y0ok && x1ok) ? mm * (1.f - ly) * lx         : 0.f;
            wt4[it][2] = (y1ok && x0ok) ? mm * ly * (1.f - lx)         : 0.f;
            wt4[it][3] = (y1ok && x1ok) ? mm * ly * lx                 : 0.f;
            int y0c = iclamp(y0, 0, HH - 1), y1c = iclamp(y1, 0, HH - 1);
            int x0c = iclamp(x0, 0, WW - 1), x1c = iclamp(x1, 0, WW - 1);
            q[it][0] = *(const u32x4*)(xb + ((size_t)y0c * WW + x0c) * 128 + cb);
            q[it][1] = *(const u32x4*)(xb + ((size_t)y0c * WW + x1c) * 128 + cb);
            q[it][2] = *(const u32x4*)(xb + ((size_t)y1c * WW + x0c) * 128 + cb);
            q[it][3] = *(const u32x4*)(xb + ((size_t)y1c * WW + x1c) * 128 + cb);
        }
        // packed-f32 bilinear combine (v_pk_fma_f32) + bf16 pack + LDS write
#pragma unroll
        for (int it = 0; it < 2; it++) {
            int p = g * 16 + it * 8 + pr;
            f32x2 wv0 = (f32x2){wt4[it][0], wt4[it][0]};
            f32x2 wv1 = (f32x2){wt4[it][1], wt4[it][1]};
            f32x2 wv2 = (f32x2){wt4[it][2], wt4[it][2]};
            f32x2 wv3 = (f32x2){wt4[it][3], wt4[it][3]};
            union { unsigned short us[8]; u32x4 v; } pk;
#pragma unroll
            for (int j = 0; j < 4; j++) {
                f32x2 v = unpk2(q[it][0][j]) * wv0;
                v = pfma(unpk2(q[it][1][j]), wv1, v);
                v = pfma(unpk2(q[it][2][j]), wv2, v);
                v = pfma(unpk2(q[it][3][j]), wv3, v);
                pk.us[2 * j]     = bf16bits(v.x);
                pk.us[2 * j + 1] = bf16bits(v.y);
            }
            *(u32x4*)(buf + ((p * 128 + cb) ^ (pr << 4))) = pk.v;
        }

        __syncthreads();

#pragma unroll
        for (int nf = 0; nf < 4; nf++) {
            int p = nf * 16 + (l & 15);
            int base = p * 128 + ((l >> 4) * 16);
            int xorr = (p & 7) << 4;
            bf16x8 bv0 = *(const bf16x8*)(buf + ((base)      ^ xorr));
            bf16x8 bv1 = *(const bf16x8*)(buf + ((base + 64) ^ xorr));
            acc[nf] = __builtin_amdgcn_mfma_f32_16x16x32_bf16(a0, bv0, acc[nf], 0, 0, 0);
            acc[nf] = __builtin_amdgcn_mfma_f32_16x16x32_bf16(a1, bv1, acc[nf], 0, 0, 0);
        }
    }

    // epilogue: bias + relu; D map col=lane&15, row=(lane>>4)*4+reg
#pragma unroll
    for (int nf = 0; nf < 4; nf++) {
#pragma unroll
        for (int rr = 0; rr < 4; rr++) {
            int o = g * 16 + (l >> 4) * 4 + rr;
            int p = nf * 16 + (l & 15);
            float v = acc[nf][rr] + bias[o];
            out[(((size_t)n * COUT + o) * HH + ho) * WW + wx * 64 + p] = fmaxf(v, 0.f);
        }
    }
}

// ---------------------------------------------------------------------------
extern "C" void kernel_launch(void* const* d_in, const int* in_sizes, int n_in,
                              void* d_out, int out_size, void* d_ws, size_t ws_size,
                              hipStream_t stream) {
    const float* x     = (const float*)d_in[0];
    const float* w_off = (const float*)d_in[1];
    const float* b_off = (const float*)d_in[2];
    const float* w_mod = (const float*)d_in[3];
    const float* b_mod = (const float*)d_in[4];
    const float* w     = (const float*)d_in[5];
    const float* b     = (const float*)d_in[6];
    float* out = (float*)d_out;

    // ws layout: wfrag bf16[36864] | wauxf bf16[18432] | baux f32[32] |
    //            xt bf16 NHWC [4*HW*64]                       (~19 MB)
    __hip_bfloat16* wfrag = (__hip_bfloat16*)d_ws;
    __hip_bfloat16* wauxf = wfrag + 36864;
    float* baux = (float*)(wauxf + 18432);
    unsigned short* xt = (unsigned short*)(baux + 32);

    to_nhwc<<<dim3(144, NB), dim3(256), 0, stream>>>(x, xt);
    prep_weights<<<dim3(144), dim3(256), 0, stream>>>(w, w_off, w_mod, b_off,
                                                      b_mod, wfrag, wauxf, baux);
    dcn_fused<<<dim3(2304), dim3(256), 0, stream>>>(xt, wfrag, wauxf, baux, b, out);
}

// Round 7
// 83.605 us; speedup vs baseline: 3.9643x; 1.0406x over previous
//
#include <hip/hip_runtime.h>
#include <hip/hip_bf16.h>
#include <math.h>

// DCNv2 forward, fully fused: aux conv (MFMA, results in LDS) -> deformable
// bilinear sampling (r=4 lane map, 2-deep software pipeline, packed f32) ->
// main conv (bf16 MFMA) + bias + relu. Input staged once as NHWC bf16.
// x [4,64,192,192] f32; w_off [18,64,3,3]; b_off[18]; w_mod [9,64,3,3]; b_mod[9];
// w [64,64,3,3]; b[64]; out [4,64,192,192] f32.

#define NB   4
#define CIN  64
#define COUT 64
#define HH   192
#define WW   192
#define HW   (HH*WW)

typedef __attribute__((ext_vector_type(4))) float f32x4;
typedef __attribute__((ext_vector_type(2))) float f32x2;
typedef __attribute__((ext_vector_type(8))) short bf16x8;
typedef __attribute__((ext_vector_type(4))) unsigned int u32x4;

__device__ __forceinline__ int iclamp(int v, int lo, int hi) {
    return v < lo ? lo : (v > hi ? hi : v);
}
__device__ __forceinline__ unsigned short bf16bits(float f) {
    __hip_bfloat16 h = __float2bfloat16(f);
    return *reinterpret_cast<unsigned short*>(&h);
}
__device__ __forceinline__ float b2f(unsigned short u) {
    union { unsigned int i; float f; } t;
    t.i = ((unsigned int)u) << 16;
    return t.f;
}
// unpack a u32 holding 2 bf16 into float2: lo = u<<16, hi = u & 0xffff0000
__device__ __forceinline__ f32x2 unpk2(unsigned int u) {
    union { unsigned int i; float f; } lo, hi;
    lo.i = u << 16;
    hi.i = u & 0xffff0000u;
    return (f32x2){lo.f, hi.f};
}
#if __has_builtin(__builtin_elementwise_fma)
__device__ __forceinline__ f32x2 pfma(f32x2 a, f32x2 b, f32x2 c) {
    return __builtin_elementwise_fma(a, b, c);
}
#else
__device__ __forceinline__ f32x2 pfma(f32x2 a, f32x2 b, f32x2 c) {
    return (f32x2){fmaf(a.x, b.x, c.x), fmaf(a.y, b.y, c.y)};
}
#endif

// ---------------------------------------------------------------------------
// Kernel A: x f32 NCHW -> xt bf16 NHWC (128 B per pixel).
// ---------------------------------------------------------------------------
__global__ __launch_bounds__(256) void to_nhwc(
        const float* __restrict__ x, unsigned short* __restrict__ xt) {
    int n  = blockIdx.y;
    int px = blockIdx.x * 256 + threadIdx.x;     // 0..HW-1
    const float* xn = x + (size_t)n * CIN * HW + px;
    union { unsigned short us[64]; u32x4 q[8]; } pk;
#pragma unroll
    for (int c = 0; c < 64; c++) pk.us[c] = bf16bits(xn[c * HW]);
    u32x4* dst = (u32x4*)(xt + ((size_t)n * HW + px) * 64);
#pragma unroll
    for (int i = 0; i < 8; i++) dst[i] = pk.q[i];
}

// ---------------------------------------------------------------------------
// Kernel 0: weight repack into MFMA A-fragment order (bf16).
//  wfrag (main, 64 out-ch): idx = (((k*4+g)*2+kc)*64 + l)*8 + j
//  wauxf (aux, 32 out-ch padded from 27): idx = ((k*4 + ga*2 + kc)*64 + l)*8 + j
//  baux  f32[32]: b_off | b_mod | 0
// ---------------------------------------------------------------------------
__global__ __launch_bounds__(256) void prep_weights(
        const float* __restrict__ w, const float* __restrict__ w_off,
        const float* __restrict__ w_mod, const float* __restrict__ b_off,
        const float* __restrict__ b_mod, __hip_bfloat16* __restrict__ wfrag,
        __hip_bfloat16* __restrict__ wauxf, float* __restrict__ baux) {
    int idx = blockIdx.x * 256 + threadIdx.x;
    if (idx < 36864) {
        int j    = idx & 7;
        int lane = (idx >> 3) & 63;
        int kc   = (idx >> 9) & 1;
        int g    = (idx >> 10) & 3;
        int k    = idx >> 12;
        int o = g * 16 + (lane & 15);
        int c = kc * 32 + (lane >> 4) * 8 + j;
        wfrag[idx] = __float2bfloat16(w[(o * 64 + c) * 9 + k]);
    }
    if (idx < 18432) {
        int j    = idx & 7;
        int lane = (idx >> 3) & 63;
        int kc   = (idx >> 9) & 1;
        int ga   = (idx >> 10) & 1;
        int k    = idx >> 11;
        int o = ga * 16 + (lane & 15);
        int c = kc * 32 + (lane >> 4) * 8 + j;
        float v = 0.f;
        if (o < 18)      v = w_off[(o * 64 + c) * 9 + k];
        else if (o < 27) v = w_mod[((o - 18) * 64 + c) * 9 + k];
        wauxf[idx] = __float2bfloat16(v);
    }
    if (idx < 32) {
        float v = 0.f;
        if (idx < 18)      v = b_off[idx];
        else if (idx < 27) v = b_mod[idx - 18];
        baux[idx] = v;
    }
}

// geometry + issue 8 corner loads (2 x b128 per corner) for tap K
#define GEOMQ(K, wt, q) do {                                                  \
    int k_ = (K);                                                             \
    int ky_ = k_ / 3, kx_ = k_ - 3 * (k_ / 3);                                \
    float offy = oml[2 * k_][p];                                              \
    float offx = oml[2 * k_ + 1][p];                                          \
    float mm   = oml[18 + k_][p];                                             \
    float py  = offy + (float)(ho - 1 + ky_);                                 \
    float pxf = offx + (float)(wox - 1 + kx_);                                \
    float y0f = floorf(py), x0f = floorf(pxf);                                \
    float ly = py - y0f, lx = pxf - x0f;                                      \
    int y0 = (int)y0f, x0 = (int)x0f;                                         \
    int y1 = y0 + 1, x1 = x0 + 1;                                             \
    bool y0ok = (unsigned)y0 < (unsigned)HH, y1ok = (unsigned)y1 < (unsigned)HH; \
    bool x0ok = (unsigned)x0 < (unsigned)WW, x1ok = (unsigned)x1 < (unsigned)WW; \
    wt[0] = (y0ok && x0ok) ? mm * (1.f - ly) * (1.f - lx) : 0.f;              \
    wt[1] = (y0ok && x1ok) ? mm * (1.f - ly) * lx         : 0.f;              \
    wt[2] = (y1ok && x0ok) ? mm * ly * (1.f - lx)         : 0.f;              \
    wt[3] = (y1ok && x1ok) ? mm * ly * lx                 : 0.f;              \
    int y0c = iclamp(y0, 0, HH - 1), y1c = iclamp(y1, 0, HH - 1);             \
    int x0c = iclamp(x0, 0, WW - 1), x1c = iclamp(x1, 0, WW - 1);             \
    const char* c00 = xb + ((size_t)y0c * WW + x0c) * 128 + cq32;             \
    const char* c01 = xb + ((size_t)y0c * WW + x1c) * 128 + cq32;             \
    const char* c10 = xb + ((size_t)y1c * WW + x0c) * 128 + cq32;             \
    const char* c11 = xb + ((size_t)y1c * WW + x1c) * 128 + cq32;             \
    q[0] = *(const u32x4*)c00; q[1] = *(const u32x4*)(c00 + 16);              \
    q[2] = *(const u32x4*)c01; q[3] = *(const u32x4*)(c01 + 16);              \
    q[4] = *(const u32x4*)c10; q[5] = *(const u32x4*)(c10 + 16);              \
    q[6] = *(const u32x4*)c11; q[7] = *(const u32x4*)(c11 + 16);              \
} while (0)

// bilinear combine + swizzled LDS write + barrier + 8 MFMA for tap K
#define TAPCM(K, BUF, wt, q) do {                                             \
    int k_ = (K);                                                             \
    char* buf = (char*)lds + (BUF) * 8192;                                    \
    f32x2 w0 = (f32x2){wt[0], wt[0]};                                         \
    f32x2 w1 = (f32x2){wt[1], wt[1]};                                         \
    f32x2 w2 = (f32x2){wt[2], wt[2]};                                         \
    f32x2 w3 = (f32x2){wt[3], wt[3]};                                         \
    _Pragma("unroll")                                                         \
    for (int half = 0; half < 2; ++half) {                                    \
        union { unsigned short us[8]; u32x4 v; } pk;                          \
        _Pragma("unroll")                                                     \
        for (int j = 0; j < 4; ++j) {                                         \
            f32x2 v = unpk2(q[half][j]) * w0;                                 \
            v = pfma(unpk2(q[2 + half][j]), w1, v);                           \
            v = pfma(unpk2(q[4 + half][j]), w2, v);                           \
            v = pfma(unpk2(q[6 + half][j]), w3, v);                           \
            pk.us[2 * j]     = bf16bits(v.x);                                 \
            pk.us[2 * j + 1] = bf16bits(v.y);                                 \
        }                                                                     \
        *(u32x4*)(buf + ((p * 128 + cq32 + half * 16) ^ swz)) = pk.v;         \
    }                                                                         \
    const bf16x8* wf = ((const bf16x8*)wfrag) + ((k_ * 4 + g) * 2) * 64 + l;  \
    bf16x8 a0 = wf[0];                                                        \
    bf16x8 a1 = wf[64];                                                       \
    __syncthreads();                                                          \
    __builtin_amdgcn_s_setprio(1);                                            \
    _Pragma("unroll")                                                         \
    for (int nf = 0; nf < 4; ++nf) {                                          \
        int pp_ = nf * 16 + (l & 15);                                         \
        int base_ = pp_ * 128 + ((l >> 4) * 16);                              \
        int xorr_ = (pp_ & 7) << 4;                                           \
        bf16x8 bv0 = *(const bf16x8*)(buf + ((base_)      ^ xorr_));          \
        bf16x8 bv1 = *(const bf16x8*)(buf + ((base_ + 64) ^ xorr_));          \
        acc[nf] = __builtin_amdgcn_mfma_f32_16x16x32_bf16(a0, bv0, acc[nf], 0, 0, 0); \
        acc[nf] = __builtin_amdgcn_mfma_f32_16x16x32_bf16(a1, bv1, acc[nf], 0, 0, 0); \
    }                                                                         \
    __builtin_amdgcn_s_setprio(0);                                            \
} while (0)

// ---------------------------------------------------------------------------
// Fused kernel. Phase A: aux conv via MFMA -> oml[32][65] in LDS.
// Phase B: r=4 sampling (lane = pixel x 32B chunk), 2-deep pipelined gathers,
// packed-f32 bilinear, swizzled LDS, MFMA main conv, bias+relu.
// ---------------------------------------------------------------------------
__global__ __launch_bounds__(256, 3) void dcn_fused(
        const unsigned short* __restrict__ xt,
        const __hip_bfloat16* __restrict__ wfrag,
        const __hip_bfloat16* __restrict__ wauxf,
        const float* __restrict__ baux,
        const float* __restrict__ bias,
        float* __restrict__ out) {
    __shared__ __align__(16) char lds[2][8192];   // val[p][c] bf16, dbuf
    __shared__ float oml[32][65];                 // aux results

    int tid = threadIdx.x;
    int l   = tid & 63;
    int g   = __builtin_amdgcn_readfirstlane(tid >> 6);

    int id = blockIdx.x;                        // 0..2303
    int sw = (id & 7) * 288 + (id >> 3);        // bijective XCD swizzle
    int n  = sw / 576;
    int r  = sw % 576;
    int ho = r / 3;
    int wx = r % 3;
    int wobase = wx * 64;

    const char* xb = (const char*)xt + (size_t)n * HW * 128;

    // ================= Phase A: aux conv for this tile =================
    {
        f32x4 aacc[2];
        aacc[0] = (f32x4){0.f, 0.f, 0.f, 0.f};
        aacc[1] = (f32x4){0.f, 0.f, 0.f, 0.f};
        const bf16x8 zero8 = (bf16x8){0, 0, 0, 0, 0, 0, 0, 0};
        int pa  = g * 16 + (l & 15);            // this lane's pixel
        int cba = (l >> 4) * 16;                // 8-ch chunk byte offset

#pragma unroll 1
        for (int k = 0; k < 9; k++) {
            int ky = k / 3, kx = k - 3 * (k / 3);
            int ys = ho + ky - 1;
            if ((unsigned)ys >= (unsigned)HH) continue;   // uniform row skip
            int xs = wobase + pa + kx - 1;
            bool ok = (unsigned)xs < (unsigned)WW;
            int xsc = iclamp(xs, 0, WW - 1);
            const char* pp = xb + ((size_t)ys * WW + xsc) * 128;
            const bf16x8* wa = ((const bf16x8*)wauxf) + (k * 4) * 64 + l;
#pragma unroll
            for (int kc = 0; kc < 2; kc++) {
                bf16x8 bv = *(const bf16x8*)(pp + kc * 64 + cba);
                if (!ok) bv = zero8;
                bf16x8 a0 = wa[(kc)     * 64];      // o 0..15
                bf16x8 a1 = wa[(2 + kc) * 64];      // o 16..31
                aacc[0] = __builtin_amdgcn_mfma_f32_16x16x32_bf16(a0, bv, aacc[0], 0, 0, 0);
                aacc[1] = __builtin_amdgcn_mfma_f32_16x16x32_bf16(a1, bv, aacc[1], 0, 0, 0);
            }
        }
#pragma unroll
        for (int h = 0; h < 2; h++) {
#pragma unroll
            for (int rr = 0; rr < 4; rr++) {
                int o = h * 16 + (l >> 4) * 4 + rr;
                float v = aacc[h][rr] + baux[o];
                if (o >= 18) v = 2.f / (1.f + expf(-v));
                oml[o][pa] = v;
            }
        }
    }
    __syncthreads();

    // ================= Phase B: deform sample + main conv =================
    f32x4 acc[4];
#pragma unroll
    for (int nf = 0; nf < 4; nf++) acc[nf] = (f32x4){0.f, 0.f, 0.f, 0.f};

    int p    = g * 16 + (l >> 2);   // this lane's pixel (r=4)
    int cq32 = (l & 3) * 32;        // 32 B chunk byte offset
    int wox  = wobase + p;          // global wo of pixel
    int swz  = (p & 7) << 4;        // LDS XOR swizzle

    float wtA[4], wtB[4];
    u32x4 qA[8], qB[8];

    GEOMQ(0, wtA, qA);
#pragma unroll 1
    for (int kk = 0; kk < 4; ++kk) {
        GEOMQ(2 * kk + 1, wtB, qB);     // prefetch tap 2kk+1
        TAPCM(2 * kk, 0, wtA, qA);      // finish tap 2kk
        GEOMQ(2 * kk + 2, wtA, qA);     // prefetch tap 2kk+2
        TAPCM(2 * kk + 1, 1, wtB, qB);  // finish tap 2kk+1
    }
    TAPCM(8, 0, wtA, qA);

    // epilogue: bias + relu; D map col=lane&15, row=(lane>>4)*4+reg
#pragma unroll
    for (int nf = 0; nf < 4; nf++) {
#pragma unroll
        for (int rr = 0; rr < 4; rr++) {
            int o = g * 16 + (l >> 4) * 4 + rr;
            int pp = nf * 16 + (l & 15);
            float v = acc[nf][rr] + bias[o];
            out[(((size_t)n * COUT + o) * HH + ho) * WW + wx * 64 + pp] = fmaxf(v, 0.f);
        }
    }
}

// ---------------------------------------------------------------------------
extern "C" void kernel_launch(void* const* d_in, const int* in_sizes, int n_in,
                              void* d_out, int out_size, void* d_ws, size_t ws_size,
                              hipStream_t stream) {
    const float* x     = (const float*)d_in[0];
    const float* w_off = (const float*)d_in[1];
    const float* b_off = (const float*)d_in[2];
    const float* w_mod = (const float*)d_in[3];
    const float* b_mod = (const float*)d_in[4];
    const float* w     = (const float*)d_in[5];
    const float* b     = (const float*)d_in[6];
    float* out = (float*)d_out;

    // ws layout: wfrag bf16[36864] | wauxf bf16[18432] | baux f32[32] |
    //            xt bf16 NHWC [4*HW*64]                       (~19 MB)
    __hip_bfloat16* wfrag = (__hip_bfloat16*)d_ws;
    __hip_bfloat16* wauxf = wfrag + 36864;
    float* baux = (float*)(wauxf + 18432);
    unsigned short* xt = (unsigned short*)(baux + 32);

    to_nhwc<<<dim3(144, NB), dim3(256), 0, stream>>>(x, xt);
    prep_weights<<<dim3(144), dim3(256), 0, stream>>>(w, w_off, w_mod, b_off,
                                                      b_mod, wfrag, wauxf, baux);
    dcn_fused<<<dim3(2304), dim3(256), 0, stream>>>(xt, wfrag, wauxf, baux, b, out);
}